// Round 1
// baseline (664.729 us; speedup 1.0000x reference)
//
#include <hip/hip_runtime.h>
#include <hip/hip_bf16.h>
#include <math.h>

#define D_MODEL 256
#define D_STATE 16
#define D_INNER 512
#define DT_RANK 16
#define NB 4
#define NVAR 32
#define SEG 96
#define TOKENS (NB*NVAR*SEG)   /* 12288 */

__device__ __forceinline__ float silu_f(float x) { return x / (1.0f + __expf(-x)); }

// ---------------------------------------------------------------------------
// Tiled NT GEMM: C[m,n] = sum_k A[m*lda+k] * W[n*K+k]
// MODE 0: plain store C[m*N+n]
// MODE 1: v = softplus(acc + bias[n]); store C[m*N+n]
// MODE 2: stage-1 out: row remap (b,v,s)->(b,s,v), ldc=256
// MODE 3: stage-2 out: row remap (b,s,v)->(b,v,s), ldc=256
// Requires: M % BM == 0, K % BK == 0, (BM/TM)*(BN/TN) == 256
// ---------------------------------------------------------------------------
template<int BM, int BN, int BK, int TM, int TN, int MODE>
__global__ __launch_bounds__(256)
void gemm_nt(const float* __restrict__ A, int lda,
             const float* __restrict__ W,
             float* __restrict__ C,
             const float* __restrict__ bias,
             int M, int N, int K)
{
    __shared__ float As[BK][BM + 4];
    __shared__ float Ws[BK][BN + 4];

    const int tid = threadIdx.x;
    const int tx  = tid % (BN / TN);
    const int ty  = tid / (BN / TN);
    const int m0  = blockIdx.x * BM;
    const int n0  = blockIdx.y * BN;

    float acc[TM][TN];
#pragma unroll
    for (int i = 0; i < TM; i++)
#pragma unroll
        for (int j = 0; j < TN; j++) acc[i][j] = 0.0f;

    constexpr int AF4 = (BM * BK) / 1024;   // float4 loads per thread for A tile
    constexpr int WF4 = (BN * BK) / 1024;
    constexpr int F4R = BK / 4;             // float4 per row

    for (int k0 = 0; k0 < K; k0 += BK) {
#pragma unroll
        for (int c = 0; c < AF4; c++) {
            int idx = tid + c * 256;
            int row = idx / F4R;
            int kc  = (idx % F4R) * 4;
            float4 v = *(const float4*)(A + (size_t)(m0 + row) * lda + k0 + kc);
            As[kc + 0][row] = v.x;
            As[kc + 1][row] = v.y;
            As[kc + 2][row] = v.z;
            As[kc + 3][row] = v.w;
        }
#pragma unroll
        for (int c = 0; c < WF4; c++) {
            int idx = tid + c * 256;
            int row = idx / F4R;
            int kc  = (idx % F4R) * 4;
            float4 v;
            if (n0 + row < N) v = *(const float4*)(W + (size_t)(n0 + row) * K + k0 + kc);
            else              v = make_float4(0.f, 0.f, 0.f, 0.f);
            Ws[kc + 0][row] = v.x;
            Ws[kc + 1][row] = v.y;
            Ws[kc + 2][row] = v.z;
            Ws[kc + 3][row] = v.w;
        }
        __syncthreads();

#pragma unroll
        for (int kk = 0; kk < BK; kk++) {
            float a[TM], w[TN];
#pragma unroll
            for (int i = 0; i < TM; i++) a[i] = As[kk][ty * TM + i];
#pragma unroll
            for (int j = 0; j < TN; j++) w[j] = Ws[kk][tx * TN + j];
#pragma unroll
            for (int i = 0; i < TM; i++)
#pragma unroll
                for (int j = 0; j < TN; j++)
                    acc[i][j] = fmaf(a[i], w[j], acc[i][j]);
        }
        __syncthreads();
    }

#pragma unroll
    for (int i = 0; i < TM; i++) {
        int m = m0 + ty * TM + i;
        int orow;
        if (MODE == 2) {            // m = (b*32+v)*96+s  ->  (b*96+s)*32+v
            int b = m / 3072, r = m % 3072;
            int v = r / 96,   s = r % 96;
            orow = (b * 96 + s) * 32 + v;
        } else if (MODE == 3) {     // m = (b*96+s)*32+v  ->  (b*32+v)*96+s
            int b = m / 3072, r = m % 3072;
            int s = r / 32,   v = r % 32;
            orow = (b * 32 + v) * 96 + s;
        } else {
            orow = m;
        }
#pragma unroll
        for (int j = 0; j < TN; j++) {
            int n = n0 + tx * TN + j;
            if (n < N) {
                float v = acc[i][j];
                if (MODE == 1) {
                    v += bias[n];
                    v = (v > 20.0f) ? v : log1pf(__expf(v));
                }
                C[(size_t)orow * N + n] = v;
            }
        }
    }
}

// ---------------------------------------------------------------------------
// Depthwise causal conv (width 4) + bias + SiLU.
// xi = xz[:, 0:512] of rows of width 1024. Output xc [tokens, 512].
// ---------------------------------------------------------------------------
__global__ __launch_bounds__(256)
void conv_silu(const float* __restrict__ xz, const float* __restrict__ cw,
               const float* __restrict__ cb, float* __restrict__ xc, int L)
{
    int i = blockIdx.x * 256 + threadIdx.x;
    int e = i % D_INNER;
    int t = i / D_INNER;          // token = bn*L + l
    int l = t % L;
    float acc = cb[e];
#pragma unroll
    for (int j = 0; j < 4; j++) {
        int li = l - 3 + j;
        if (li >= 0) acc = fmaf(xz[(size_t)(t + li - l) * 1024 + e], cw[e * 4 + j], acc);
    }
    xc[i] = silu_f(acc);
}

// ---------------------------------------------------------------------------
// Selective scan + skip + gate.  One thread per (bn, channel e).
// dty: in = dt (softplus'ed), out = gated y (in place).
// ---------------------------------------------------------------------------
__global__ __launch_bounds__(256)
void scan_gate(float* __restrict__ dty,
               const float* __restrict__ xc,
               const float* __restrict__ xz,      // z = cols 512..1023
               const float* __restrict__ dbl,     // [tokens,48]: dt|B|C
               const float* __restrict__ A_log,
               const float* __restrict__ Dvec,
               int L)
{
    int bn = blockIdx.x >> 1;
    int e  = ((blockIdx.x & 1) << 8) + threadIdx.x;

    float Ae[D_STATE], h[D_STATE];
#pragma unroll
    for (int s = 0; s < D_STATE; s++) {
        Ae[s] = -__expf(A_log[e * D_STATE + s]);
        h[s]  = 0.0f;
    }
    const float De = Dvec[e];

    for (int l = 0; l < L; l++) {
        int tk = bn * L + l;
        float dtv = dty[(size_t)tk * 512 + e];
        float u   = xc [(size_t)tk * 512 + e];
        float zv  = xz [(size_t)tk * 1024 + 512 + e];
        const float* bc = dbl + (size_t)tk * 48;
        float y = 0.0f;
#pragma unroll
        for (int s = 0; s < D_STATE; s++) {
            float dA = __expf(dtv * Ae[s]);
            h[s] = fmaf(dA, h[s], dtv * bc[16 + s] * u);
            y    = fmaf(h[s], bc[32 + s], y);
        }
        dty[(size_t)tk * 512 + e] = (y + u * De) * silu_f(zv);
    }
}

// ---------------------------------------------------------------------------
// One mamba stage.
// ---------------------------------------------------------------------------
template<int OUTMODE>
static void run_stage(const float* xin,
                      const float* in_w, const float* conv_w, const float* conv_b,
                      const float* xproj_w, const float* dt_w, const float* dt_b,
                      const float* A_log, const float* Dvec, const float* out_w,
                      float* xz, float* xc, float* dbl, float* dty, float* outp,
                      int Bn, int L, hipStream_t stream)
{
    const int M = TOKENS;
    // in_proj: [M,1024] = x[M,256] * in_w[1024,256]^T
    gemm_nt<128,128,16,8,8,0><<<dim3(M/128, 1024/128), 256, 0, stream>>>(
        xin, 256, in_w, xz, nullptr, M, 1024, 256);
    // conv + silu
    conv_silu<<<dim3((M * D_INNER) / 256), 256, 0, stream>>>(xz, conv_w, conv_b, xc, L);
    // x_proj: [M,48] = xc[M,512] * xproj_w[48,512]^T
    gemm_nt<64,64,16,4,4,0><<<dim3(M/64, 1), 256, 0, stream>>>(
        xc, 512, xproj_w, dbl, nullptr, M, 48, 512);
    // dt_proj + softplus: [M,512] = dbl[:, :16] * dt_w[512,16]^T + dt_b
    gemm_nt<128,64,16,8,4,1><<<dim3(M/128, 512/64), 256, 0, stream>>>(
        dbl, 48, dt_w, dty, dt_b, M, 512, 16);
    // scan + skip + gate (y written over dty)
    scan_gate<<<dim3(Bn * 2), 256, 0, stream>>>(dty, xc, xz, dbl, A_log, Dvec, L);
    // out_proj with fused layout transpose
    gemm_nt<128,64,16,8,4,OUTMODE><<<dim3(M/128, 256/64), 256, 0, stream>>>(
        dty, 512, out_w, outp, nullptr, M, 256, 512);
}

extern "C" void kernel_launch(void* const* d_in, const int* in_sizes, int n_in,
                              void* d_out, int out_size, void* d_ws, size_t ws_size,
                              hipStream_t stream)
{
    const float* x = (const float*)d_in[0];
    const float* t_in_w    = (const float*)d_in[1];
    const float* t_conv_w  = (const float*)d_in[2];
    const float* t_conv_b  = (const float*)d_in[3];
    const float* t_xproj_w = (const float*)d_in[4];
    const float* t_dt_w    = (const float*)d_in[5];
    const float* t_dt_b    = (const float*)d_in[6];
    const float* t_A_log   = (const float*)d_in[7];
    const float* t_D       = (const float*)d_in[8];
    const float* t_out_w   = (const float*)d_in[9];
    const float* d_in_w    = (const float*)d_in[10];
    const float* d_conv_w  = (const float*)d_in[11];
    const float* d_conv_b  = (const float*)d_in[12];
    const float* d_xproj_w = (const float*)d_in[13];
    const float* d_dt_w    = (const float*)d_in[14];
    const float* d_dt_b    = (const float*)d_in[15];
    const float* d_A_log   = (const float*)d_in[16];
    const float* d_D       = (const float*)d_in[17];
    const float* d_out_w   = (const float*)d_in[18];

    float* ws  = (float*)d_ws;
    float* xz  = ws;                                     // 12288*1024
    float* xc  = xz  + (size_t)TOKENS * 1024;            // 12288*512
    float* dbl = xc  + (size_t)TOKENS * 512;             // 12288*48
    float* dty = dbl + (size_t)TOKENS * 48;              // 12288*512
    float* xt  = dty + (size_t)TOKENS * 512;             // 12288*256
    const size_t need_bytes = ((size_t)TOKENS * (1024 + 512 + 48 + 512 + 256)) * 4;
    if (ws_size < need_bytes) return;   // fail loudly (output stays wrong)

    // stage 1: time scan over SEG, Bn = B*NVAR = 128, L = 96
    run_stage<2>(x, t_in_w, t_conv_w, t_conv_b, t_xproj_w, t_dt_w, t_dt_b,
                 t_A_log, t_D, t_out_w, xz, xc, dbl, dty, xt,
                 NB * NVAR, SEG, stream);
    // stage 2: dimension scan over NVAR, Bn = B*SEG = 384, L = 32
    run_stage<3>(xt, d_in_w, d_conv_w, d_conv_b, d_xproj_w, d_dt_w, d_dt_b,
                 d_A_log, d_D, d_out_w, xz, xc, dbl, dty, (float*)d_out,
                 NB * SEG, NVAR, stream);
}